// Round 11
// baseline (452.774 us; speedup 1.0000x reference)
//
#include <hip/hip_runtime.h>

#define T_LEN  4096
#define KS     16
#define NCHUNK 256      // T_LEN / 16
#define LEAD   6        // consumer lags producers by 6 chunks
#define SLOTS  8        // LDS ring slots
#define BU_PAD 20       // bu row stride in dwords
#define TCOLS  65       // tile row stride: (lane*65+col) mod 32 -> 2-way max (free)

#define ALPHA_F 0.9048374180359595f
#define BETA_F  0.09516258196404048f
#define THETA_F 0.5f

// --- reduce pieces via builtins: compiler schedules DPP hazards and can
// interleave surrounding work into the wait slots (R1-proven correct). ------
template<int CTRL>
__device__ __forceinline__ float dpp_max(float v) {
  int r = __builtin_amdgcn_update_dpp(0, __float_as_int(v), CTRL, 0xF, 0xF, true);
  return fmaxf(v, __int_as_float(r));
}
__device__ __forceinline__ float swap32_max(float v) {
#if __has_builtin(__builtin_amdgcn_permlane32_swap)
  auto r = __builtin_amdgcn_permlane32_swap(__float_as_int(v), __float_as_int(v), false, false);
  return fmaxf(__int_as_float((int)r[0]), __int_as_float((int)r[1]));
#else
  return fmaxf(v, __shfl_xor(v, 32, 64));
#endif
}
__device__ __forceinline__ float swap16_max(float v) {
#if __has_builtin(__builtin_amdgcn_permlane16_swap)
  auto r = __builtin_amdgcn_permlane16_swap(__float_as_int(v), __float_as_int(v), false, false);
  return fmaxf(__int_as_float((int)r[0]), __int_as_float((int)r[1]));
#else
  return fmaxf(v, __shfl_xor(v, 16, 64));
#endif
}
__device__ __forceinline__ float wave64_max_all(float v) {
  float m = v;
  m = dpp_max<0xB1>(m);   // xor1  (quad_perm 1,0,3,2)
  m = dpp_max<0x4E>(m);   // xor2  (quad_perm 2,3,0,1)
  m = dpp_max<0x141>(m);  // xor7  (row_half_mirror)
  m = dpp_max<0x140>(m);  // xor15 (row_mirror)
  m = swap32_max(m);
  m = swap16_max(m);
  return m;
}

// dst = mask[lane] ? a : b   (64-bit SGPR-pair mask as cndmask condition; VALU)
__device__ __forceinline__ unsigned sel_mask_u(unsigned long long msk,
                                               unsigned a, unsigned b) {
  unsigned d;
  asm("v_cndmask_b32 %0, %2, %1, %3" : "=v"(d) : "v"(a), "v"(b), "s"(msk));
  return d;
}

__global__ __launch_bounds__(192, 1)
void convlif_wta_kernel(const float* __restrict__ x, const float* __restrict__ W,
                        float* __restrict__ out) {
  const int b    = blockIdx.x;
  const int wave = threadIdx.x >> 6;   // 0,1 = producers(+flush); 2 = consumer
  const int lane = threadIdx.x & 63;   // channel k

  __shared__ float bu_lds[SLOTS][64][BU_PAD];   // 40 KB  (conv ring)
  __shared__ float tile[2][64][TCOLS];          // 32.5 KB (spike tile, dbuf)

  float* outB = out + (size_t)b * 64 * T_LEN;

  if (wave < 2) {
    // ========== producers: causal conv + tile flush, x prefetched =========
    float w[KS];
    {
      const float4* w4 = reinterpret_cast<const float4*>(W + lane * KS);
      #pragma unroll
      for (int q = 0; q < 4; ++q) {
        float4 a = w4[q];
        w[4*q+0] = a.x; w[4*q+1] = a.y; w[4*q+2] = a.z; w[4*q+3] = a.w;
      }
    }
    const float4* xv4 = reinterpret_cast<const float4*>(x + (size_t)b * T_LEN);

    // xw[m] = x[16*c - 16 + m] for my current chunk c (x[<0] = 0)
    float xw[32];
    {
      const int c0 = wave;            // my first chunk (0 or 1)
      if (c0 == 0) {
        #pragma unroll
        for (int m = 0; m < 16; ++m) xw[m] = 0.0f;
        #pragma unroll
        for (int q = 0; q < 4; ++q) {
          float4 a = xv4[q];
          xw[16+4*q+0] = a.x; xw[16+4*q+1] = a.y;
          xw[16+4*q+2] = a.z; xw[16+4*q+3] = a.w;
        }
      } else {
        #pragma unroll
        for (int q = 0; q < 8; ++q) {
          float4 a = xv4[q];          // quads 4*c0-4 .. 4*c0+3 = 0..7
          xw[4*q+0] = a.x; xw[4*q+1] = a.y; xw[4*q+2] = a.z; xw[4*q+3] = a.w;
        }
      }
    }

    for (int s = 0; s < NCHUNK + LEAD + 1; ++s) {
      if (s < NCHUNK && (s & 1) == wave) {
        const int c = s;

        // issue next-parity chunk's loads NOW; conv below hides the latency
        float4 nx[8];
        {
          const int cn = (c + 2 < NCHUNK) ? c + 2 : c;   // safe clamp
          const int bq = 4 * cn - 4;
          #pragma unroll
          for (int q = 0; q < 8; ++q) nx[q] = xv4[bq + q];
        }

        // u[t=16c+i] = sum_j w[j]*x[t-15+j]; summation order identical to R10
        float u[16];
        #pragma unroll
        for (int i = 0; i < 16; ++i) {
          float acc = w[0] * xw[1 + i];
          #pragma unroll
          for (int j = 1; j < KS; ++j) acc = fmaf(w[j], xw[1 + i + j], acc);
          u[i] = BETA_F * acc;
        }

        float4* dst = reinterpret_cast<float4*>(&bu_lds[c & (SLOTS-1)][lane][0]);
        dst[0] = make_float4(u[0],  u[1],  u[2],  u[3]);
        dst[1] = make_float4(u[4],  u[5],  u[6],  u[7]);
        dst[2] = make_float4(u[8],  u[9],  u[10], u[11]);
        dst[3] = make_float4(u[12], u[13], u[14], u[15]);

        // rotate prefetched window in (full window advance, no overlap)
        #pragma unroll
        for (int q = 0; q < 8; ++q) {
          xw[4*q+0] = nx[q].x; xw[4*q+1] = nx[q].y;
          xw[4*q+2] = nx[q].z; xw[4*q+3] = nx[q].w;
        }
      }

      // flush completed 64-step tile T at s = 4T+10 (consumer finished it at
      // s-1; barrier below orders LDS writes -> these reads). Consumer reuses
      // the buffer starting s = 4T+14 -> no overlap.
      if (s >= 10 && (s & 3) == 2) {
        const int T = (s - 10) >> 2;
        if (T < T_LEN / 64) {
          const int pl   = wave * 64 + lane;   // 0..127
          const int colq = (pl & 15) * 4;      // 0,4,...,60
          const int r0   = pl >> 4;            // 0..7
          const float* tb = &tile[T & 1][0][0];
          #pragma unroll
          for (int it = 0; it < 8; ++it) {
            const int r = r0 + it * 8;
            const float* src = tb + r * TCOLS + colq;   // scalar ds reads
            float4 vq = make_float4(src[0], src[1], src[2], src[3]);
            *reinterpret_cast<float4*>(&outB[(size_t)r * T_LEN + T * 64 + colq]) = vq;
          }
        }
      }
      __syncthreads();
    }
  } else {
    // ===== consumer: VALU-pure LIF + WTA (no branches, no SALU reads) =====
    float v = 0.0f;
    float4 b0, b1, b2, b3;

    for (int s = 0; s < NCHUNK + LEAD + 1; ++s) {
      if (s == LEAD - 1) {
        const float4* src = reinterpret_cast<const float4*>(&bu_lds[0][lane][0]);
        b0 = src[0]; b1 = src[1]; b2 = src[2]; b3 = src[3];
      } else if (s >= LEAD && s < NCHUNK + LEAD) {
        const int c = s - LEAD;
        float bu[16] = { b0.x, b0.y, b0.z, b0.w,  b1.x, b1.y, b1.z, b1.w,
                         b2.x, b2.y, b2.z, b2.w,  b3.x, b3.y, b3.z, b3.w };

        float sv[16];

        #pragma unroll
        for (int i = 0; i < 16; ++i) {
          v = fmaf(ALPHA_F, v, bu[i]);          // same arithmetic as R10
          float vm = v - THETA_F;               // exact; (vm>=0) <=> (v>=theta)

          // always-reduce, all-VALU winner determination:
          float m = wave64_max_all(v);
          // gate: if global max < theta nobody fires (INF matches no lane)
          float mgate = (m >= THETA_F) ? m : __builtin_inff();
          unsigned long long eq = __ballot(v == mgate);   // v_cmp -> sgpr pair
          unsigned cnt = __builtin_amdgcn_mbcnt_hi(
              (unsigned)(eq >> 32),
              __builtin_amdgcn_mbcnt_lo((unsigned)eq, 0u)); // VALU reads sgprs
          // cnt2: eq lanes -> # eq lanes below; non-eq lanes -> 1 (nonzero)
          unsigned cnt2 = sel_mask_u(eq, cnt, 1u);
          bool win = (cnt2 == 0u);              // first eq lane = argmax winner

          sv[i] = win ? 1.0f : 0.0f;
          v     = win ? vm : v;                 // v - s*theta, exact
        }

        // flush chunk results: 4 x ds_write_b128, conflict-free (TCOLS=65)
        float* trow = &tile[(c >> 2) & 1][lane][(c & 3) * 16];
        *reinterpret_cast<float4*>(trow +  0) = make_float4(sv[0],  sv[1],  sv[2],  sv[3]);
        *reinterpret_cast<float4*>(trow +  4) = make_float4(sv[4],  sv[5],  sv[6],  sv[7]);
        *reinterpret_cast<float4*>(trow +  8) = make_float4(sv[8],  sv[9],  sv[10], sv[11]);
        *reinterpret_cast<float4*>(trow + 12) = make_float4(sv[12], sv[13], sv[14], sv[15]);

        // prefetch next chunk's bu (produced >= 1 barrier ago; slot safe)
        if (c + 1 < NCHUNK) {
          const float4* src =
              reinterpret_cast<const float4*>(&bu_lds[(c + 1) & (SLOTS-1)][lane][0]);
          b0 = src[0]; b1 = src[1]; b2 = src[2]; b3 = src[3];
        }
      }
      __syncthreads();
    }
  }
}

extern "C" void kernel_launch(void* const* d_in, const int* in_sizes, int n_in,
                              void* d_out, int out_size, void* d_ws, size_t ws_size,
                              hipStream_t stream) {
  const float* x   = (const float*)d_in[0];
  const float* W   = (const float*)d_in[1];
  float*       out = (float*)d_out;
  convlif_wta_kernel<<<dim3(256), dim3(192), 0, stream>>>(x, W, out);
}

// Round 12
// 261.616 us; speedup vs baseline: 1.7307x; 1.7307x over previous
//
#include <hip/hip_runtime.h>

#define T_LEN  4096
#define KS     16
#define NCHUNK 256      // T_LEN / 16
#define LEAD   6        // consumer lags producers by 6 chunks
#define SLOTS  8        // LDS ring slots
#define BU_PAD 20       // bu row stride in dwords
#define TCOLS  65       // tile row stride: (lane*65+col) mod 32 -> 2-way max (free)

#define ALPHA_F 0.9048374180359595f
#define BETA_F  0.09516258196404048f
#define THETA_F 0.5f

// Full-wave (64-lane) max, result in ALL lanes. 4 fused DPP max levels, then
// permlane32_swap / permlane16_swap + max. Manual s_nop 1 before every
// DPP/permlane consumer (VALU->DPP needs 2 wait states; compiler can't see
// inside the asm block). Verbatim from the passing R3/R4/R5/R7/R8/R10 kernels.
__device__ __forceinline__ float wave64_max_all(float v) {
  float m, t;
  asm("s_nop 1\n\t"
      "v_max_f32 %0, %2, %2 quad_perm:[1,0,3,2] row_mask:0xf bank_mask:0xf\n\t"
      "s_nop 1\n\t"
      "v_max_f32 %0, %0, %0 quad_perm:[2,3,0,1] row_mask:0xf bank_mask:0xf\n\t"
      "s_nop 1\n\t"
      "v_max_f32 %0, %0, %0 row_half_mirror row_mask:0xf bank_mask:0xf\n\t"
      "s_nop 1\n\t"
      "v_max_f32 %0, %0, %0 row_mirror row_mask:0xf bank_mask:0xf\n\t"
      "v_mov_b32 %1, %0\n\t"
      "s_nop 1\n\t"
      "v_permlane32_swap_b32 %1, %0\n\t"
      "s_nop 1\n\t"
      "v_max_f32 %0, %0, %1\n\t"
      "v_mov_b32 %1, %0\n\t"
      "s_nop 1\n\t"
      "v_permlane16_swap_b32 %1, %0\n\t"
      "s_nop 1\n\t"
      "v_max_f32 %0, %0, %1"
      : "=&v"(m), "=&v"(t)
      : "v"(v));
  return m;
}

// dst = mask[lane] ? a : b   (64-bit SGPR-pair mask as cndmask condition; VALU)
__device__ __forceinline__ float sel_mask(unsigned long long msk, float a, float b) {
  float d;
  asm("v_cndmask_b32 %0, %2, %1, %3" : "=v"(d) : "v"(a), "v"(b), "s"(msk));
  return d;
}

__global__ __launch_bounds__(256, 1)
void convlif_wta_kernel(const float* __restrict__ x, const float* __restrict__ W,
                        float* __restrict__ out) {
  const int b    = blockIdx.x;
  const int wave = threadIdx.x >> 6;   // 0,1,2 = producers(+flush); 3 = consumer
  const int lane = threadIdx.x & 63;   // channel k

  __shared__ float bu_lds[SLOTS][64][BU_PAD];   // 40 KB  (conv ring)
  __shared__ float tile[2][64][TCOLS];          // 32.5 KB (spike tile, dbuf)

  float* outB = out + (size_t)b * 64 * T_LEN;

  if (wave < 3) {
    // ====== producers: causal conv (round-robin mod 3) + tile flush =======
    float w[KS];
    {
      const float4* w4 = reinterpret_cast<const float4*>(W + lane * KS);
      #pragma unroll
      for (int q = 0; q < 4; ++q) {
        float4 a = w4[q];
        w[4*q+0] = a.x; w[4*q+1] = a.y; w[4*q+2] = a.z; w[4*q+3] = a.w;
      }
    }
    const float4* xv4 = reinterpret_cast<const float4*>(x + (size_t)b * T_LEN);

    int myc = wave;   // my next chunk (wave, wave+3, wave+6, ...)

    for (int s = 0; s < NCHUNK + LEAD + 1; ++s) {
      if (s == myc && s < NCHUNK) {
        const int c = s;
        myc += 3;

        // xf[m] = x[16c-16+m], m = 0..31 (x[<0] treated as 0)
        float xf[32];
        if (c == 0) {
          #pragma unroll
          for (int m = 0; m < 16; ++m) xf[m] = 0.0f;
        } else {
          const int b4 = 4 * c - 4;
          #pragma unroll
          for (int q = 0; q < 4; ++q) {
            float4 a = xv4[b4 + q];
            xf[4*q+0] = a.x; xf[4*q+1] = a.y; xf[4*q+2] = a.z; xf[4*q+3] = a.w;
          }
        }
        #pragma unroll
        for (int q = 0; q < 4; ++q) {
          float4 a = xv4[4*c + q];
          xf[16+4*q+0] = a.x; xf[16+4*q+1] = a.y;
          xf[16+4*q+2] = a.z; xf[16+4*q+3] = a.w;
        }

        // u[t=16c+i] = sum_j w[j]*x[t-15+j]; summation order identical to R10
        float u[16];
        #pragma unroll
        for (int i = 0; i < 16; ++i) {
          float acc = w[0] * xf[1 + i];
          #pragma unroll
          for (int j = 1; j < KS; ++j) acc = fmaf(w[j], xf[1 + i + j], acc);
          u[i] = BETA_F * acc;
        }

        float4* dst = reinterpret_cast<float4*>(&bu_lds[c & (SLOTS-1)][lane][0]);
        dst[0] = make_float4(u[0],  u[1],  u[2],  u[3]);
        dst[1] = make_float4(u[4],  u[5],  u[6],  u[7]);
        dst[2] = make_float4(u[8],  u[9],  u[10], u[11]);
        dst[3] = make_float4(u[12], u[13], u[14], u[15]);
      }

      // flush completed 64-step tile T at s = 4T+10 (consumer finished it at
      // s-1; barrier below orders LDS writes -> these reads). Consumer reuses
      // the buffer starting s = 4T+14 -> no overlap. 192 threads, 1024 quads.
      if (s >= 10 && (s & 3) == 2) {
        const int T = (s - 10) >> 2;
        if (T < T_LEN / 64) {
          const int pl = wave * 64 + lane;     // 0..191
          const float* tb = &tile[T & 1][0][0];
          #pragma unroll
          for (int k = 0; k < 6; ++k) {
            const int idx = pl + 192 * k;      // 0..1151
            if (idx < 1024) {
              const int r  = idx >> 4;         // 0..63
              const int cq = (idx & 15) * 4;   // 0,4,...,60
              const float* src = tb + r * TCOLS + cq;
              float4 vq = make_float4(src[0], src[1], src[2], src[3]);
              *reinterpret_cast<float4*>(&outB[(size_t)r * T_LEN + T * 64 + cq]) = vq;
            }
          }
        }
      }
      __syncthreads();
    }
  } else {
    // ========= consumer: LIF + WTA (verbatim R10 — the A/B control) =======
    float v = 0.0f;
    float4 b0, b1, b2, b3;

    for (int s = 0; s < NCHUNK + LEAD + 1; ++s) {
      if (s == LEAD - 1) {
        const float4* src = reinterpret_cast<const float4*>(&bu_lds[0][lane][0]);
        b0 = src[0]; b1 = src[1]; b2 = src[2]; b3 = src[3];
      } else if (s >= LEAD && s < NCHUNK + LEAD) {
        const int c = s - LEAD;
        float bu[16] = { b0.x, b0.y, b0.z, b0.w,  b1.x, b1.y, b1.z, b1.w,
                         b2.x, b2.y, b2.z, b2.w,  b3.x, b3.y, b3.z, b3.w };

        float sv[16];

        #pragma unroll
        for (int i = 0; i < 16; ++i) {
          v = fmaf(ALPHA_F, v, bu[i]);          // same arithmetic as R10
          float vm = v - THETA_F;               // exact; (vm>=0) <=> (v>=theta)

          unsigned long long sp = __ballot(v >= THETA_F);
          unsigned long long msk;
          if (__builtin_expect(__builtin_popcountll(sp) > 1, 0)) {
            // >=2 candidates (rare): winner = first lane attaining global max
            float m = wave64_max_all(v);
            unsigned long long eq = __ballot(v == m);
            msk = eq & (0ull - eq);             // lowest max lane = argmax
          } else {
            // 0 or 1 candidate: sp IS the winner mask (possibly empty)
            msk = sp;
          }

          sv[i] = sel_mask(msk, 1.0f, 0.0f);    // spike value
          v     = sel_mask(msk, vm, v);         // v - s*theta, exact
        }

        // flush chunk results: 4 x ds_write_b128, conflict-free (TCOLS=65)
        float* trow = &tile[(c >> 2) & 1][lane][(c & 3) * 16];
        *reinterpret_cast<float4*>(trow +  0) = make_float4(sv[0],  sv[1],  sv[2],  sv[3]);
        *reinterpret_cast<float4*>(trow +  4) = make_float4(sv[4],  sv[5],  sv[6],  sv[7]);
        *reinterpret_cast<float4*>(trow +  8) = make_float4(sv[8],  sv[9],  sv[10], sv[11]);
        *reinterpret_cast<float4*>(trow + 12) = make_float4(sv[12], sv[13], sv[14], sv[15]);

        // prefetch next chunk's bu (produced >= 1 barrier ago; slot safe)
        if (c + 1 < NCHUNK) {
          const float4* src =
              reinterpret_cast<const float4*>(&bu_lds[(c + 1) & (SLOTS-1)][lane][0]);
          b0 = src[0]; b1 = src[1]; b2 = src[2]; b3 = src[3];
        }
      }
      __syncthreads();
    }
  }
}

extern "C" void kernel_launch(void* const* d_in, const int* in_sizes, int n_in,
                              void* d_out, int out_size, void* d_ws, size_t ws_size,
                              hipStream_t stream) {
  const float* x   = (const float*)d_in[0];
  const float* W   = (const float*)d_in[1];
  float*       out = (float*)d_out;
  convlif_wta_kernel<<<dim3(256), dim3(256), 0, stream>>>(x, W, out);
}